// Round 9
// baseline (607.188 us; speedup 1.0000x reference)
//
#include <hip/hip_runtime.h>
#include <hip/hip_bf16.h>
#include <cstdio>
#include <cstdint>

#define B_SZ    2
#define L_SEQ   1024
#define DMODEL  768
#define DINNER  1536
#define DSTATE  16
#define DTRANK  48
#define VOCAB   32000
#define BL      (B_SZ * L_SEQ)   // 2048
#define NCH     64               // scan chunks per sequence
#define CLEN    16               // timesteps per chunk (NCH*CLEN == L_SEQ)

typedef __bf16 bf16;
typedef __bf16 bf16x8 __attribute__((ext_vector_type(8)));
typedef __bf16 bf16x4 __attribute__((ext_vector_type(4)));
typedef float  f32x4  __attribute__((ext_vector_type(4)));

// ---------------- async global->LDS (16B/lane, wave-uniform base + lane*16) --
__device__ __forceinline__ void gload16(const void* g, void* l) {
  __builtin_amdgcn_global_load_lds(
      (const __attribute__((address_space(1))) void*)g,
      (__attribute__((address_space(3))) void*)l, 16, 0, 0);
}
__device__ __forceinline__ void memfence() { asm volatile("" ::: "memory"); }

// ---------------- embedding gather fused with hi/lo bf16 split --------------
__global__ void k_embed(const int* __restrict__ ids, const float* __restrict__ emb,
                        bf16* __restrict__ xh, bf16* __restrict__ xl) {
  const int row = blockIdx.x;
  const int id  = ids[row];
  const float4* s = (const float4*)(emb + (size_t)id * DMODEL);
  const int i = threadIdx.x;             // 192 threads = DMODEL/4
  const float4 v = s[i];
  bf16x4 hv, lv;
  hv[0] = (bf16)v.x; hv[1] = (bf16)v.y; hv[2] = (bf16)v.z; hv[3] = (bf16)v.w;
  lv[0] = (bf16)(v.x - (float)hv[0]); lv[1] = (bf16)(v.y - (float)hv[1]);
  lv[2] = (bf16)(v.z - (float)hv[2]); lv[3] = (bf16)(v.w - (float)hv[3]);
  *(bf16x4*)(xh + (size_t)row * DMODEL + i * 4) = hv;
  *(bf16x4*)(xl + (size_t)row * DMODEL + i * 4) = lv;
}

// ---------------- weight transpose + convert: W(K,N) f32 -> WT(N,K) bf16 ----
template<bool SPLIT>
__global__ void k_tconv(const float* __restrict__ W, bf16* __restrict__ Th,
                        bf16* __restrict__ Tl, int K, int N) {
  __shared__ float t[32][33];
  const int n0 = blockIdx.x * 32;
  const int k0 = blockIdx.y * 32;
  const int tx = threadIdx.x;   // 0..31
  const int ty = threadIdx.y;   // 0..7
#pragma unroll
  for (int i = 0; i < 4; i++)
    t[ty + i * 8][tx] = W[(size_t)(k0 + ty + i * 8) * N + n0 + tx];
  __syncthreads();
#pragma unroll
  for (int i = 0; i < 4; i++) {
    const float v = t[tx][ty + i * 8];
    const bf16 hv = (bf16)v;
    Th[(size_t)(n0 + ty + i * 8) * K + k0 + tx] = hv;
    if constexpr (SPLIT)
      Tl[(size_t)(n0 + ty + i * 8) * K + k0 + tx] = (bf16)(v - (float)hv);
  }
}

// ---------------- bf16 MFMA GEMM, 128x128, A-direct + B-LDS 2-buf -----------
// Round-9: A fragments loaded DIRECTLY from global (L1/L2-hot, per-lane
// dwordx4) — removes A staging + A ds_reads; LDS holds only B (32 KB SPLIT).
// stage B(t+1) before compute(t); one vmcnt(0)+barrier per K-tile.
// SPLIT: AhBh + AlBh + AhBl. BF16OUT: write C as bf16 (fused cvt).
template<bool SPLIT, bool BIAS, bool BF16OUT>
__global__ __launch_bounds__(256) void k_gemm(
    const bf16* __restrict__ Ah, const bf16* __restrict__ Al,
    const bf16* __restrict__ Bh, const bf16* __restrict__ Bl,
    const float* __restrict__ bias, float* __restrict__ C,
    int M, int N, int K) {
  __shared__ bf16 sBh[2][128 * 32];
  __shared__ bf16 sBl[SPLIT ? 2 : 1][SPLIT ? 128 * 32 : 8];

  const int tid  = threadIdx.x;
  const int lane = tid & 63;
  const int wave = tid >> 6;
  const int bm = blockIdx.y * 128;
  const int bn = blockIdx.x * 128;

  const int srow = tid >> 2;         // 0..63: staging row
  const int schk = (tid & 3) * 8;    // element offset in 32-wide K slab

  const bf16* gB0 = Bh + (size_t)(bn + srow) * K + schk;
  const bf16* gB1 = gB0 + (size_t)64 * K;
  const bf16 *gB0l = nullptr, *gB1l = nullptr;
  if constexpr (SPLIT) {
    gB0l = Bl + (size_t)(bn + srow) * K + schk;  gB1l = gB0l + (size_t)64 * K;
  }

  const int wm = (wave >> 1) * 64;
  const int wn = (wave & 1) * 64;
  const int lr = lane & 15;
  const int kg = lane >> 4;

  // A-direct per-lane fragment pointers (frag mi: rows wm+mi*16+lr)
  const bf16* gAh[4];
  const bf16* gAl[4];
#pragma unroll
  for (int mi = 0; mi < 4; mi++) {
    gAh[mi] = Ah + (size_t)(bm + wm + mi * 16 + lr) * K + kg * 8;
    if constexpr (SPLIT)
      gAl[mi] = Al + (size_t)(bm + wm + mi * 16 + lr) * K + kg * 8;
  }

  f32x4 acc[4][4] = {};
  const int nt = K >> 5;

#define STG(t_, b_) do {                                                    \
    const size_t ko_ = (size_t)(t_) * 32;                                   \
    gload16(gB0 + ko_, &sBh[b_][tid * 8]);                                  \
    gload16(gB1 + ko_, &sBh[b_][2048 + tid * 8]);                           \
    if constexpr (SPLIT) {                                                  \
      gload16(gB0l + ko_, &sBl[b_][tid * 8]);                               \
      gload16(gB1l + ko_, &sBl[b_][2048 + tid * 8]);                        \
    }                                                                       \
  } while (0)

  STG(0, 0);
  asm volatile("s_waitcnt vmcnt(0)" ::: "memory");
  __builtin_amdgcn_s_barrier();
  memfence();

  for (int t = 0; t < nt; ++t) {
    const int b = t & 1;
    const int ko = t * 32;

    // A fragments direct from global (compiler inserts vmcnt deps)
    bf16x8 af[4];
#pragma unroll
    for (int i = 0; i < 4; i++) af[i] = *(const bf16x8*)(gAh[i] + ko);

    if (t + 1 < nt) STG(t + 1, b ^ 1);   // overlap next-tile B staging

    bf16x8 bfv[4];
#pragma unroll
    for (int i = 0; i < 4; i++)
      bfv[i] = *(const bf16x8*)&sBh[b][(wn + i * 16 + lr) * 32 + kg * 8];

#pragma unroll
    for (int mi = 0; mi < 4; mi++)
#pragma unroll
      for (int ni = 0; ni < 4; ni++)
        acc[mi][ni] = __builtin_amdgcn_mfma_f32_16x16x32_bf16(
            af[mi], bfv[ni], acc[mi][ni], 0, 0, 0);

    if constexpr (SPLIT) {
      bf16x8 afl[4], bfl[4];
#pragma unroll
      for (int i = 0; i < 4; i++) afl[i] = *(const bf16x8*)(gAl[i] + ko);
#pragma unroll
      for (int i = 0; i < 4; i++)
        bfl[i] = *(const bf16x8*)&sBl[b][(wn + i * 16 + lr) * 32 + kg * 8];
#pragma unroll
      for (int mi = 0; mi < 4; mi++)
#pragma unroll
        for (int ni = 0; ni < 4; ni++) {
          acc[mi][ni] = __builtin_amdgcn_mfma_f32_16x16x32_bf16(
              afl[mi], bfv[ni], acc[mi][ni], 0, 0, 0);
          acc[mi][ni] = __builtin_amdgcn_mfma_f32_16x16x32_bf16(
              af[mi], bfl[ni], acc[mi][ni], 0, 0, 0);
        }
    }

    asm volatile("s_waitcnt vmcnt(0)" ::: "memory");  // next B tile landed
    __builtin_amdgcn_s_barrier();                     // buf swap safe
    memfence();
  }
#undef STG

#pragma unroll
  for (int mi = 0; mi < 4; mi++) {
#pragma unroll
    for (int ni = 0; ni < 4; ni++) {
      const int col = bn + wn + ni * 16 + lr;
      float bv = 0.f;
      if constexpr (BIAS) bv = bias[col];
#pragma unroll
      for (int r = 0; r < 4; r++) {
        const int row = bm + wm + mi * 16 + kg * 4 + r;
        if constexpr (BF16OUT)
          ((bf16*)C)[(size_t)row * N + col] = (bf16)(acc[mi][ni][r] + bv);
        else
          C[(size_t)row * N + col] = acc[mi][ni][r] + bv;
      }
    }
  }
}

// ========== 128x256 8-wave GEMM: A-direct + B-LDS 2-buf (lm_head) ===========
// Round-9 theory: r4/r5/r8 all pinned at ~150us / 28% MfmaUtil across three
// schedules -> invariant LDS traffic was the wall (A+B reads ~= MFMA cycles,
// chained serially per wave). A (3 MB) is L1/L2-resident and reused across
// all 125 N-panels -> load A frags global->VGPR directly; LDS only stages B
// (16 KB/buf x2 = 32 KB). LDS read burst halves; MFMA becomes binding pipe.
// B swizzle unchanged: slot' = slot ^ ((row>>1)&3), linear gload dest,
// inverse-permuted source, same XOR on read (row+128 preserves the key).
__global__ __launch_bounds__(512, 4) void k_gemm8(
    const bf16* __restrict__ A, const bf16* __restrict__ Bt,
    const float* __restrict__ bias, float* __restrict__ C,
    int M, int N, int K, int mblocks) {
  extern __shared__ bf16 lds[];   // [2 bufs][B 8192 el]

  // T1: bijective XCD swizzle (gridDim.x % 8 == 0 guaranteed by host)
  const int orig = (blockIdx.x & 7) * ((int)gridDim.x >> 3) + (blockIdx.x >> 3);
  const int bm = (orig % mblocks) * 128;
  const int bn = (orig / mblocks) * 256;

  const int tid  = threadIdx.x;
  const int lane = tid & 63;
  const int wave = tid >> 6;       // 0..7
  const int wm   = wave >> 2;      // 0..1 : M half (64 rows)
  const int wn   = wave & 3;       // 0..3 : N quarter (64 cols)
  const int lr   = lane & 15;
  const int kg   = lane >> 4;      // 0..3 : 16B k-slot
  const int sw   = (lr >> 1) & 3;  // read-side swizzle key

  // B staging: inst0 rows [16w,16w+16), inst1 rows 128+[16w,16w+16)
  const int srB = (wave << 4) + (lane >> 2);
  const int ssB = (lane & 3) ^ ((srB >> 1) & 3);   // +128 rows: same key
  const size_t gBoff0 = (size_t)(bn + srB) * K + ssB * 8;
  const size_t gBoff1 = gBoff0 + (size_t)128 * K;

  // A-direct per-lane fragment pointers (frag i: rows wm*64+i*16+lr)
  const bf16* gA[4];
#pragma unroll
  for (int i = 0; i < 4; i++)
    gA[i] = A + (size_t)(bm + wm * 64 + i * 16 + lr) * K + kg * 8;

  // B fragment read offsets within a buffer (elements, swizzled)
  const int boff = (wn * 64 + lr) * 32 + ((kg ^ sw) << 3);

  const int nt = K >> 5;   // 24

#define STAGE_B(ts_) do {                                                  \
    bf16* lb_ = lds + ((ts_) & 1) * 8192;                                  \
    const size_t ko_ = (size_t)(ts_) * 32;                                 \
    gload16(Bt + gBoff0 + ko_, lb_ + tid * 8);                             \
    gload16(Bt + gBoff1 + ko_, lb_ + 4096 + tid * 8);                      \
  } while (0)

  f32x4 acc[4][4] = {};

  STAGE_B(0);
  asm volatile("s_waitcnt vmcnt(0)" ::: "memory");
  __builtin_amdgcn_s_barrier();
  memfence();

  for (int t = 0; t < nt; ++t) {
    const int ko = t * 32;

    // A fragments direct from global (L1/L2-hot; compiler inserts vmcnt deps)
    bf16x8 afr[4];
#pragma unroll
    for (int i = 0; i < 4; i++) afr[i] = *(const bf16x8*)(gA[i] + ko);

    if (t + 1 < nt) STAGE_B(t + 1);   // issue next-tile B staging

    const bf16* lB = lds + (t & 1) * 8192;
    bf16x8 bfr[4];
#pragma unroll
    for (int j = 0; j < 4; j++) bfr[j] = *(const bf16x8*)(lB + boff + j * 512);

    __builtin_amdgcn_s_setprio(1);
#pragma unroll
    for (int i = 0; i < 4; i++)
#pragma unroll
      for (int j = 0; j < 4; j++)
        acc[i][j] = __builtin_amdgcn_mfma_f32_16x16x32_bf16(afr[i], bfr[j], acc[i][j], 0, 0, 0);
    __builtin_amdgcn_s_setprio(0);

    asm volatile("s_waitcnt vmcnt(0)" ::: "memory");  // B(t+1) landed
    __builtin_amdgcn_s_barrier();
    memfence();
  }
#undef STAGE_B

  // epilogue: C/D layout col=lane&15, row=(lane>>4)*4+r
  float bv[4];
#pragma unroll
  for (int j = 0; j < 4; j++)
    bv[j] = bias ? bias[bn + wn * 64 + j * 16 + lr] : 0.f;
#pragma unroll
  for (int i = 0; i < 4; i++) {
    const int row = bm + wm * 64 + i * 16 + kg * 4;
#pragma unroll
    for (int j = 0; j < 4; j++) {
      const int col = bn + wn * 64 + j * 16 + lr;
#pragma unroll
      for (int r = 0; r < 4; r++)
        C[(size_t)(row + r) * N + col] = acc[i][j][r] + bv[j];
    }
  }
}

// ---------------- depthwise causal conv (D_CONV=4) + silu -------------------
__global__ void k_conv(const float* __restrict__ xz, const float* __restrict__ cw,
                       const float* __restrict__ cb, float* __restrict__ xa) {
  const int bl = blockIdx.x;
  const int l  = bl & (L_SEQ - 1);
  for (int d = threadIdx.x; d < DINNER; d += blockDim.x) {
    float acc = cb[d];
#pragma unroll
    for (int k = 0; k < 4; k++) {
      const int ll = l + k - 3;
      if (ll >= 0)
        acc = fmaf(xz[(size_t)(bl + k - 3) * (2 * DINNER) + d], cw[d * 4 + k], acc);
    }
    xa[(size_t)bl * DINNER + d] = acc / (1.f + __expf(-acc));
  }
}

// ---------------- x_proj: dbl(2048,80) = xa(2048,1536) @ w(1536,80), fp32 ---
__global__ void k_xproj(const float* __restrict__ xa, const float* __restrict__ w,
                        float* __restrict__ dbl) {
  const int t = threadIdx.x;               // 640 = 8 rows x 80 cols
  const int r = blockIdx.x * 8 + t / 80;
  const int c = t % 80;
  const float* xr = xa + (size_t)r * DINNER;
  float acc = 0.f;
  for (int k = 0; k < DINNER; k++) acc = fmaf(xr[k], w[k * 80 + c], acc);
  dbl[(size_t)r * 80 + c] = acc;
}

// ---------------- dt_proj + softplus, 8 rows/block (w_dt L2 reuse x8) -------
__global__ __launch_bounds__(256) void k_dtproj(
    const float* __restrict__ dbl, const float* __restrict__ w,
    const float* __restrict__ bvec, float* __restrict__ dt) {
  const int r0 = blockIdx.x * 8;
  const int tid = threadIdx.x;
  __shared__ float ds[8][DTRANK];
  for (int i = tid; i < 8 * DTRANK; i += 256)
    ds[i / DTRANK][i % DTRANK] = dbl[(size_t)(r0 + i / DTRANK) * 80 + i % DTRANK];
  __syncthreads();
  for (int c = tid; c < DINNER; c += 256) {
    const float bvc = bvec[c];
    float acc[8];
#pragma unroll
    for (int j = 0; j < 8; j++) acc[j] = bvc;
    for (int k = 0; k < DTRANK; k++) {
      const float wv = w[(size_t)k * DINNER + c];
#pragma unroll
      for (int j = 0; j < 8; j++) acc[j] = fmaf(ds[j][k], wv, acc[j]);
    }
#pragma unroll
    for (int j = 0; j < 8; j++) {
      const float a = acc[j];
      dt[(size_t)(r0 + j) * DINNER + c] = (a > 20.f) ? a : log1pf(expf(a));
    }
  }
}

// ======================= chunk-parallel selective scan =======================
__global__ __launch_bounds__(256) void k_scan1(
    const float* __restrict__ dt, const float* __restrict__ dbl,
    const float* __restrict__ xa, const float* __restrict__ a_log,
    float* __restrict__ P, float* __restrict__ S) {
  const int tid = threadIdx.x;
  const int d = blockIdx.x * 256 + tid;
  const int c = blockIdx.y;
  const int b = blockIdx.z;
  __shared__ float sB[CLEN][DSTATE];
  {
    const int j = tid >> 4, n = tid & 15;
    sB[j][n] = dbl[(size_t)(b * L_SEQ + c * CLEN + j) * 80 + DTRANK + n];
  }
  __syncthreads();
  float a[16];
#pragma unroll
  for (int q = 0; q < 4; q++) {
    const float4 v = *(const float4*)&a_log[d * DSTATE + q * 4];
    a[q*4+0] = -expf(v.x); a[q*4+1] = -expf(v.y);
    a[q*4+2] = -expf(v.z); a[q*4+3] = -expf(v.w);
  }
  float h[16] = {}, p[16];
#pragma unroll
  for (int n = 0; n < 16; n++) p[n] = 1.f;
  const size_t rowb = (size_t)(b * L_SEQ + c * CLEN);
#pragma unroll 4
  for (int j = 0; j < CLEN; j++) {
    const size_t row = rowb + j;
    const float dtv = dt[row * DINNER + d];
    const float xav = xa[row * DINNER + d];
    const float du  = dtv * xav;
#pragma unroll
    for (int n = 0; n < 16; n++) {
      const float dA = __expf(dtv * a[n]);
      h[n] = fmaf(dA, h[n], du * sB[j][n]);
      p[n] *= dA;
    }
  }
  const size_t base = (((size_t)c * B_SZ + b) * DINNER + d) * DSTATE;
#pragma unroll
  for (int q = 0; q < 4; q++) {
    *(float4*)&P[base + q * 4] = make_float4(p[q*4], p[q*4+1], p[q*4+2], p[q*4+3]);
    *(float4*)&S[base + q * 4] = make_float4(h[q*4], h[q*4+1], h[q*4+2], h[q*4+3]);
  }
}

__global__ __launch_bounds__(256) void k_scan2(
    const float* __restrict__ P, const float* __restrict__ S,
    float* __restrict__ Hin) {
  const int gid = blockIdx.x * 256 + threadIdx.x;   // (b*DINNER+d)*16+n
  const int STRIDE = B_SZ * DINNER * DSTATE;        // 49152
  float h = 0.f;
#pragma unroll 4
  for (int c = 0; c < NCH; c++) {
    Hin[(size_t)c * STRIDE + gid] = h;
    h = fmaf(P[(size_t)c * STRIDE + gid], h, S[(size_t)c * STRIDE + gid]);
  }
}

// scan3: re-scan with true h0, fused epilogue, writes hi/lo bf16 split of
// ycmb directly (feeds out_proj A operand)
__global__ __launch_bounds__(256) void k_scan3(
    const float* __restrict__ dt, const float* __restrict__ dbl,
    const float* __restrict__ xa, const float* __restrict__ a_log,
    const float* __restrict__ dvec, const float* __restrict__ xz,
    const float* __restrict__ Hin, bf16* __restrict__ ych,
    bf16* __restrict__ ycl) {
  const int tid = threadIdx.x;
  const int d = blockIdx.x * 256 + tid;
  const int c = blockIdx.y;
  const int b = blockIdx.z;
  __shared__ float sB[CLEN][DSTATE];
  __shared__ float sC[CLEN][DSTATE];
  {
    const int j = tid >> 4, n = tid & 15;
    const size_t r80 = (size_t)(b * L_SEQ + c * CLEN + j) * 80;
    sB[j][n] = dbl[r80 + DTRANK + n];
    sC[j][n] = dbl[r80 + DTRANK + DSTATE + n];
  }
  __syncthreads();
  float a[16];
#pragma unroll
  for (int q = 0; q < 4; q++) {
    const float4 v = *(const float4*)&a_log[d * DSTATE + q * 4];
    a[q*4+0] = -expf(v.x); a[q*4+1] = -expf(v.y);
    a[q*4+2] = -expf(v.z); a[q*4+3] = -expf(v.w);
  }
  float h[16];
  const size_t base = (((size_t)c * B_SZ + b) * DINNER + d) * DSTATE;
#pragma unroll
  for (int q = 0; q < 4; q++) {
    const float4 v = *(const float4*)&Hin[base + q * 4];
    h[q*4+0] = v.x; h[q*4+1] = v.y; h[q*4+2] = v.z; h[q*4+3] = v.w;
  }
  const float Dv = dvec[d];
  const size_t rowb = (size_t)(b * L_SEQ + c * CLEN);
#pragma unroll 4
  for (int j = 0; j < CLEN; j++) {
    const size_t row = rowb + j;
    const float dtv = dt[row * DINNER + d];
    const float xav = xa[row * DINNER + d];
    const float du  = dtv * xav;
    float y = 0.f;
#pragma unroll
    for (int n = 0; n < 16; n++) {
      const float dA = __expf(dtv * a[n]);
      h[n] = fmaf(dA, h[n], du * sB[j][n]);
      y = fmaf(h[n], sC[j][n], y);
    }
    const float z  = xz[row * (2 * DINNER) + DINNER + d];
    const float sz = z / (1.f + __expf(-z));
    const float val = fmaf(xav, Dv, y) * sz;
    const bf16 hv = (bf16)val;
    ych[row * DINNER + d] = hv;
    ycl[row * DINNER + d] = (bf16)(val - (float)hv);
  }
}

// ============================================================================
extern "C" void kernel_launch(void* const* d_in, const int* in_sizes, int n_in,
                              void* d_out, int out_size, void* d_ws, size_t ws_size,
                              hipStream_t stream) {
  const int*   ids   = (const int*)d_in[0];
  const float* emb   = (const float*)d_in[1];
  const float* w_in  = (const float*)d_in[2];   // 768 x 3072
  const float* cw    = (const float*)d_in[3];   // 1536 x 4
  const float* cb    = (const float*)d_in[4];
  const float* w_x   = (const float*)d_in[5];   // 1536 x 80
  const float* w_dt  = (const float*)d_in[6];   // 48 x 1536
  const float* b_dt  = (const float*)d_in[7];
  const float* a_log = (const float*)d_in[8];   // 1536 x 16
  const float* dvec  = (const float*)d_in[9];
  const float* w_out = (const float*)d_in[10];  // 1536 x 768
  const float* w_lm  = (const float*)d_in[11];  // 768 x 32000
  const float* b_lm  = (const float*)d_in[12];
  float* out = (float*)d_out;

  char* ws = (char*)d_ws;
  size_t off = 0;
  auto alloc = [&](size_t bytes) {
    void* p = ws + off;
    off = (off + bytes + 255) & ~(size_t)255;
    return p;
  };
  float* xw    = (float*)alloc((size_t)BL * DMODEL * 4);   // (unused; layout kept)
  float* xz    = (float*)alloc((size_t)BL * 2 * DINNER * 4);
  float* xa    = (float*)alloc((size_t)BL * DINNER * 4);
  float* dbl   = (float*)alloc((size_t)BL * 80 * 4);
  float* dt    = (float*)alloc((size_t)BL * DINNER * 4);
  float* ycmb  = (float*)alloc((size_t)BL * DINNER * 4);   // (unused; layout kept)
  float* yo    = (float*)alloc((size_t)BL * DMODEL * 4);   // (unused; layout kept)
  bf16* xwh    = (bf16*)alloc((size_t)BL * DMODEL * 2);
  bf16* xwl    = (bf16*)alloc((size_t)BL * DMODEL * 2);
  bf16* wtinh  = (bf16*)alloc((size_t)3072 * DMODEL * 2);
  bf16* wtinl  = (bf16*)alloc((size_t)3072 * DMODEL * 2);
  bf16* ych    = (bf16*)alloc((size_t)BL * DINNER * 2);
  bf16* ycl    = (bf16*)alloc((size_t)BL * DINNER * 2);
  bf16* wtoh   = (bf16*)alloc((size_t)DMODEL * DINNER * 2);
  bf16* wtol   = (bf16*)alloc((size_t)DMODEL * DINNER * 2);
  bf16* yob    = (bf16*)alloc((size_t)BL * DMODEL * 2);
  bf16* wtlm   = (bf16*)alloc((size_t)VOCAB * DMODEL * 2);
  (void)xw; (void)ycmb; (void)yo;
  if (off > ws_size) {
    fprintf(stderr, "kernel_launch: ws too small (need %zu, have %zu)\n", off, ws_size);
    return;
  }

  // Scan scratch aliased onto dead-lifetime regions:
  //  P -> xwh+xwl (dead after in_proj GEMM); S -> ych+ycl (scan3 writes them
  //  AFTER scan2 consumed S); Hin -> wtlm (overwritten by lm tconv after scan3)
  float* Pbuf = (float*)xwh;
  float* Sbuf = (float*)ych;
  float* Hin  = (float*)wtlm;

  (void)hipFuncSetAttribute((const void*)k_gemm8,
                            hipFuncAttributeMaxDynamicSharedMemorySize, 65536);

  // 1. embed fused with hi/lo split
  k_embed<<<BL, DMODEL / 4, 0, stream>>>(ids, emb, xwh, xwl);
  // 2. transpose-convert in_proj weight
  k_tconv<true><<<dim3(3072 / 32, DMODEL / 32), dim3(32, 8), 0, stream>>>(w_in, wtinh, wtinl, DMODEL, 3072);
  // 3. in_proj GEMM (split, fp32-exact-ish): xz = xw @ w_in
  k_gemm<true, false, false><<<dim3(3072 / 128, BL / 128), 256, 0, stream>>>(
      xwh, xwl, wtinh, wtinl, nullptr, xz, BL, 3072, DMODEL);
  // 4. conv + silu
  k_conv<<<BL, 256, 0, stream>>>(xz, cw, cb, xa);
  // 5. x_proj (fp32)
  k_xproj<<<BL / 8, 640, 0, stream>>>(xa, w_x, dbl);
  // 6. dt_proj + softplus (fp32, 8 rows/block)
  k_dtproj<<<BL / 8, 256, 0, stream>>>(dbl, w_dt, b_dt, dt);
  // 7. chunk-parallel scan; scan3 writes split bf16 directly
  k_scan1<<<dim3(DINNER / 256, NCH, B_SZ), 256, 0, stream>>>(dt, dbl, xa, a_log, Pbuf, Sbuf);
  k_scan2<<<(B_SZ * DINNER * DSTATE) / 256, 256, 0, stream>>>(Pbuf, Sbuf, Hin);
  k_scan3<<<dim3(DINNER / 256, NCH, B_SZ), 256, 0, stream>>>(dt, dbl, xa, a_log, dvec, xz, Hin, ych, ycl);
  // 8. out_proj GEMM (split), bf16 output fused (yob)
  k_tconv<true><<<dim3(DMODEL / 32, DINNER / 32), dim3(32, 8), 0, stream>>>(w_out, wtoh, wtol, DINNER, DMODEL);
  k_gemm<true, false, true><<<dim3(DMODEL / 128, BL / 128), 256, 0, stream>>>(
      ych, ycl, wtoh, wtol, nullptr, (float*)yob, BL, DMODEL, DINNER);
  // 9. lm_head GEMM: 128x256 A-direct + B-LDS 2-buf, bf16 + fp32 bias
  k_tconv<false><<<dim3(VOCAB / 32, DMODEL / 32), dim3(32, 8), 0, stream>>>(w_lm, wtlm, nullptr, DMODEL, VOCAB);
  {
    const int mb = BL / 128;                 // 16
    const int nb = VOCAB / 256;              // 125
    k_gemm8<<<mb * nb, 512, 32768, stream>>>(yob, wtlm, b_lm, out,
                                             BL, VOCAB, DMODEL, mb);
  }
}

// Round 10
// 481.979 us; speedup vs baseline: 1.2598x; 1.2598x over previous
//
#include <hip/hip_runtime.h>
#include <hip/hip_bf16.h>
#include <cstdio>
#include <cstdint>

#define B_SZ    2
#define L_SEQ   1024
#define DMODEL  768
#define DINNER  1536
#define DSTATE  16
#define DTRANK  48
#define VOCAB   32000
#define BL      (B_SZ * L_SEQ)   // 2048
#define NCH     64               // scan chunks per sequence
#define CLEN    16               // timesteps per chunk (NCH*CLEN == L_SEQ)
#define NKT     (DMODEL / 32)    // 24 K-tiles for lm_head

typedef __bf16 bf16;
typedef __bf16 bf16x8 __attribute__((ext_vector_type(8)));
typedef __bf16 bf16x4 __attribute__((ext_vector_type(4)));
typedef float  f32x4  __attribute__((ext_vector_type(4)));

// ---------------- async global->LDS (16B/lane, wave-uniform base + lane*16) --
__device__ __forceinline__ void gload16(const void* g, void* l) {
  __builtin_amdgcn_global_load_lds(
      (const __attribute__((address_space(1))) void*)g,
      (__attribute__((address_space(3))) void*)l, 16, 0, 0);
}
__device__ __forceinline__ void memfence() { asm volatile("" ::: "memory"); }

// ---------------- embedding gather fused with hi/lo bf16 split --------------
__global__ void k_embed(const int* __restrict__ ids, const float* __restrict__ emb,
                        bf16* __restrict__ xh, bf16* __restrict__ xl) {
  const int row = blockIdx.x;
  const int id  = ids[row];
  const float4* s = (const float4*)(emb + (size_t)id * DMODEL);
  const int i = threadIdx.x;             // 192 threads = DMODEL/4
  const float4 v = s[i];
  bf16x4 hv, lv;
  hv[0] = (bf16)v.x; hv[1] = (bf16)v.y; hv[2] = (bf16)v.z; hv[3] = (bf16)v.w;
  lv[0] = (bf16)(v.x - (float)hv[0]); lv[1] = (bf16)(v.y - (float)hv[1]);
  lv[2] = (bf16)(v.z - (float)hv[2]); lv[3] = (bf16)(v.w - (float)hv[3]);
  *(bf16x4*)(xh + (size_t)row * DMODEL + i * 4) = hv;
  *(bf16x4*)(xl + (size_t)row * DMODEL + i * 4) = lv;
}

// ---------------- weight transpose + convert: W(K,N) f32 -> WT(N,K) bf16 ----
template<bool SPLIT>
__global__ void k_tconv(const float* __restrict__ W, bf16* __restrict__ Th,
                        bf16* __restrict__ Tl, int K, int N) {
  __shared__ float t[32][33];
  const int n0 = blockIdx.x * 32;
  const int k0 = blockIdx.y * 32;
  const int tx = threadIdx.x;   // 0..31
  const int ty = threadIdx.y;   // 0..7
#pragma unroll
  for (int i = 0; i < 4; i++)
    t[ty + i * 8][tx] = W[(size_t)(k0 + ty + i * 8) * N + n0 + tx];
  __syncthreads();
#pragma unroll
  for (int i = 0; i < 4; i++) {
    const float v = t[tx][ty + i * 8];
    const bf16 hv = (bf16)v;
    Th[(size_t)(n0 + ty + i * 8) * K + k0 + tx] = hv;
    if constexpr (SPLIT)
      Tl[(size_t)(n0 + ty + i * 8) * K + k0 + tx] = (bf16)(v - (float)hv);
  }
}

// ------- lm_head weight: W(K,N) f32 -> packed MFMA B-fragments bf16 ---------
// Bp[(nt*NKT + kt)*512 + lane*8 + j] = W[kt*32 + (lane>>4)*8 + j][nt*16 + (lane&15)]
// => a wave's B-frag load is 64 lanes x 16B CONTIGUOUS (1KB coalesced).
__global__ void k_tconvp(const float* __restrict__ W, bf16* __restrict__ Bp,
                         int K, int N) {
  __shared__ float t[32][33];
  const int n0 = blockIdx.x * 32;
  const int k0 = blockIdx.y * 32;
  const int tx = threadIdx.x;   // 0..31
  const int ty = threadIdx.y;   // 0..7
#pragma unroll
  for (int i = 0; i < 4; i++)
    t[ty + i * 8][tx] = W[(size_t)(k0 + ty + i * 8) * N + n0 + tx];
  __syncthreads();
  const int kt = k0 >> 5;
#pragma unroll
  for (int i = 0; i < 4; i++) {
    const int n = n0 + ty + i * 8;
    const int k = k0 + tx;
    const float v = t[tx][ty + i * 8];
    const int l = (((k & 31) >> 3) << 4) | (n & 15);   // kg*16 + lr
    Bp[((size_t)(n >> 4) * NKT + kt) * 512 + l * 8 + (k & 7)] = (bf16)v;
  }
}

// ------- pack A (row-major bf16, K=768) into MFMA A-fragments ---------------
__global__ void k_apack(const bf16* __restrict__ A, bf16* __restrict__ Ap) {
  const int mt = blockIdx.x;    // 0..127
  const int kt = blockIdx.y;    // 0..NKT-1
  const int l  = threadIdx.x;   // 0..63
  const int lr = l & 15, kg = l >> 4;
  const bf16x8 v = *(const bf16x8*)(A + (size_t)(mt * 16 + lr) * DMODEL + kt * 32 + kg * 8);
  *(bf16x8*)(Ap + ((size_t)mt * NKT + kt) * 512 + l * 8) = v;
}

// ---------------- bf16 MFMA GEMM, 128x128, A+B LDS 2-buf (round-8 form) -----
// stage(t+1) issued BEFORE compute(t); one vmcnt(0)+barrier per K-tile.
// SPLIT: AhBh + AlBh + AhBl. BF16OUT: write C as bf16 (fused cvt).
template<bool SPLIT, bool BIAS, bool BF16OUT>
__global__ __launch_bounds__(256) void k_gemm(
    const bf16* __restrict__ Ah, const bf16* __restrict__ Al,
    const bf16* __restrict__ Bh, const bf16* __restrict__ Bl,
    const float* __restrict__ bias, float* __restrict__ C,
    int M, int N, int K) {
  __shared__ bf16 sAh[2][128 * 32];
  __shared__ bf16 sBh[2][128 * 32];
  __shared__ bf16 sAl[SPLIT ? 2 : 1][SPLIT ? 128 * 32 : 8];
  __shared__ bf16 sBl[SPLIT ? 2 : 1][SPLIT ? 128 * 32 : 8];

  const int tid  = threadIdx.x;
  const int lane = tid & 63;
  const int wave = tid >> 6;
  const int bm = blockIdx.y * 128;
  const int bn = blockIdx.x * 128;

  const int srow = tid >> 2;         // 0..63: staging row
  const int schk = (tid & 3) * 8;    // element offset in 32-wide K slab

  const bf16* gA0 = Ah + (size_t)(bm + srow) * K + schk;
  const bf16* gA1 = gA0 + (size_t)64 * K;
  const bf16* gB0 = Bh + (size_t)(bn + srow) * K + schk;
  const bf16* gB1 = gB0 + (size_t)64 * K;
  const bf16 *gA0l = nullptr, *gA1l = nullptr, *gB0l = nullptr, *gB1l = nullptr;
  if constexpr (SPLIT) {
    gA0l = Al + (size_t)(bm + srow) * K + schk;  gA1l = gA0l + (size_t)64 * K;
    gB0l = Bl + (size_t)(bn + srow) * K + schk;  gB1l = gB0l + (size_t)64 * K;
  }

  const int wm = (wave >> 1) * 64;
  const int wn = (wave & 1) * 64;
  const int lr = lane & 15;
  const int kg = lane >> 4;

  f32x4 acc[4][4] = {};
  const int nt = K >> 5;

#define STG(t_, b_) do {                                                    \
    const size_t ko_ = (size_t)(t_) * 32;                                   \
    gload16(gA0 + ko_, &sAh[b_][tid * 8]);                                  \
    gload16(gA1 + ko_, &sAh[b_][2048 + tid * 8]);                           \
    gload16(gB0 + ko_, &sBh[b_][tid * 8]);                                  \
    gload16(gB1 + ko_, &sBh[b_][2048 + tid * 8]);                           \
    if constexpr (SPLIT) {                                                  \
      gload16(gA0l + ko_, &sAl[b_][tid * 8]);                               \
      gload16(gA1l + ko_, &sAl[b_][2048 + tid * 8]);                        \
      gload16(gB0l + ko_, &sBl[b_][tid * 8]);                               \
      gload16(gB1l + ko_, &sBl[b_][2048 + tid * 8]);                        \
    }                                                                       \
  } while (0)

  STG(0, 0);
  asm volatile("s_waitcnt vmcnt(0)" ::: "memory");
  __builtin_amdgcn_s_barrier();
  memfence();

  for (int t = 0; t < nt; ++t) {
    const int b = t & 1;
    if (t + 1 < nt) STG(t + 1, b ^ 1);   // overlap next-tile staging w/ compute

    bf16x8 af[4], bfv[4];
#pragma unroll
    for (int i = 0; i < 4; i++)
      af[i] = *(const bf16x8*)&sAh[b][(wm + i * 16 + lr) * 32 + kg * 8];
#pragma unroll
    for (int i = 0; i < 4; i++)
      bfv[i] = *(const bf16x8*)&sBh[b][(wn + i * 16 + lr) * 32 + kg * 8];

#pragma unroll
    for (int mi = 0; mi < 4; mi++)
#pragma unroll
      for (int ni = 0; ni < 4; ni++)
        acc[mi][ni] = __builtin_amdgcn_mfma_f32_16x16x32_bf16(
            af[mi], bfv[ni], acc[mi][ni], 0, 0, 0);

    if constexpr (SPLIT) {
      bf16x8 afl[4], bfl[4];
#pragma unroll
      for (int i = 0; i < 4; i++)
        afl[i] = *(const bf16x8*)&sAl[b][(wm + i * 16 + lr) * 32 + kg * 8];
#pragma unroll
      for (int i = 0; i < 4; i++)
        bfl[i] = *(const bf16x8*)&sBl[b][(wn + i * 16 + lr) * 32 + kg * 8];
#pragma unroll
      for (int mi = 0; mi < 4; mi++)
#pragma unroll
        for (int ni = 0; ni < 4; ni++) {
          acc[mi][ni] = __builtin_amdgcn_mfma_f32_16x16x32_bf16(
              afl[mi], bfv[ni], acc[mi][ni], 0, 0, 0);
          acc[mi][ni] = __builtin_amdgcn_mfma_f32_16x16x32_bf16(
              af[mi], bfl[ni], acc[mi][ni], 0, 0, 0);
        }
    }

    asm volatile("s_waitcnt vmcnt(0)" ::: "memory");  // next tile landed
    __builtin_amdgcn_s_barrier();                     // all waves done w/ buf b
    memfence();
  }
#undef STG

#pragma unroll
  for (int mi = 0; mi < 4; mi++) {
#pragma unroll
    for (int ni = 0; ni < 4; ni++) {
      const int col = bn + wn + ni * 16 + lr;
      float bv = 0.f;
      if constexpr (BIAS) bv = bias[col];
#pragma unroll
      for (int r = 0; r < 4; r++) {
        const int row = bm + wm + mi * 16 + kg * 4 + r;
        if constexpr (BF16OUT)
          ((bf16*)C)[(size_t)row * N + col] = (bf16)(acc[mi][ni][r] + bv);
        else
          C[(size_t)row * N + col] = acc[mi][ni][r] + bv;
      }
    }
  }
}

// ========== lm_head GEMM: packed-fragment direct-global, no LDS/barriers ====
// Round-10 theory: the 150us plateau (r4/r5/r8, 3 schedules) is the LDS
// round-trip forced by layout mismatch; r9 showed naive A-direct shatters
// coalescing (16 rows/wave-load). Fix: operands PRE-PACKED so each MFMA
// fragment is 64 lanes x 16B contiguous -> coalesced dwordx4, L1/L2-served.
// 128x128 block, 4 waves (64x64 each), register double-buffered K-loop,
// free-running waves (no sync at all), 3 blocks/CU.
__global__ __launch_bounds__(256, 3) void k_gemmp(
    const bf16* __restrict__ Ap, const bf16* __restrict__ Bp,
    const float* __restrict__ bias, float* __restrict__ C,
    int M, int N, int mblocks) {
  // T1: bijective XCD swizzle (gridDim.x % 8 == 0)
  const int orig = (blockIdx.x & 7) * ((int)gridDim.x >> 3) + (blockIdx.x >> 3);
  const int bm = (orig % mblocks) * 128;
  const int bn = (orig / mblocks) * 128;

  const int lane = threadIdx.x & 63;
  const int wave = threadIdx.x >> 6;   // 0..3
  const int wm   = wave >> 1;          // 0..1
  const int wn   = wave & 1;           // 0..1
  const int lr   = lane & 15;
  const int kg   = lane >> 4;

  const bf16* pA = Ap + ((size_t)((bm >> 4) + wm * 4) * NKT) * 512 + lane * 8;
  const bf16* pB = Bp + ((size_t)((bn >> 4) + wn * 4) * NKT) * 512 + lane * 8;
  // frag i at pA + i*NKT*512 + kt*512

  f32x4 acc[4][4] = {};
  bf16x8 a0[4], b0[4], a1[4], b1[4];

#pragma unroll
  for (int i = 0; i < 4; i++) {
    a0[i] = *(const bf16x8*)(pA + (size_t)i * NKT * 512);
    b0[i] = *(const bf16x8*)(pB + (size_t)i * NKT * 512);
  }

#pragma unroll 1
  for (int kt = 0; kt < NKT; kt += 2) {
    // prefetch kt+1 into reg-buf 1
#pragma unroll
    for (int i = 0; i < 4; i++) {
      a1[i] = *(const bf16x8*)(pA + (size_t)i * NKT * 512 + (kt + 1) * 512);
      b1[i] = *(const bf16x8*)(pB + (size_t)i * NKT * 512 + (kt + 1) * 512);
    }
#pragma unroll
    for (int i = 0; i < 4; i++)
#pragma unroll
      for (int j = 0; j < 4; j++)
        acc[i][j] = __builtin_amdgcn_mfma_f32_16x16x32_bf16(a0[i], b0[j], acc[i][j], 0, 0, 0);

    // prefetch kt+2 into reg-buf 0
    if (kt + 2 < NKT) {
#pragma unroll
      for (int i = 0; i < 4; i++) {
        a0[i] = *(const bf16x8*)(pA + (size_t)i * NKT * 512 + (kt + 2) * 512);
        b0[i] = *(const bf16x8*)(pB + (size_t)i * NKT * 512 + (kt + 2) * 512);
      }
    }
#pragma unroll
    for (int i = 0; i < 4; i++)
#pragma unroll
      for (int j = 0; j < 4; j++)
        acc[i][j] = __builtin_amdgcn_mfma_f32_16x16x32_bf16(a1[i], b1[j], acc[i][j], 0, 0, 0);
  }

  // epilogue: C/D layout col=lane&15, row=(lane>>4)*4+r
  float bv[4];
#pragma unroll
  for (int j = 0; j < 4; j++)
    bv[j] = bias[bn + wn * 64 + j * 16 + lr];
#pragma unroll
  for (int i = 0; i < 4; i++) {
    const int row = bm + wm * 64 + i * 16 + kg * 4;
#pragma unroll
    for (int j = 0; j < 4; j++) {
      const int col = bn + wn * 64 + j * 16 + lr;
#pragma unroll
      for (int r = 0; r < 4; r++)
        C[(size_t)(row + r) * N + col] = acc[i][j][r] + bv[j];
    }
  }
}

// ---------------- depthwise causal conv (D_CONV=4) + silu -------------------
__global__ void k_conv(const float* __restrict__ xz, const float* __restrict__ cw,
                       const float* __restrict__ cb, float* __restrict__ xa) {
  const int bl = blockIdx.x;
  const int l  = bl & (L_SEQ - 1);
  for (int d = threadIdx.x; d < DINNER; d += blockDim.x) {
    float acc = cb[d];
#pragma unroll
    for (int k = 0; k < 4; k++) {
      const int ll = l + k - 3;
      if (ll >= 0)
        acc = fmaf(xz[(size_t)(bl + k - 3) * (2 * DINNER) + d], cw[d * 4 + k], acc);
    }
    xa[(size_t)bl * DINNER + d] = acc / (1.f + __expf(-acc));
  }
}

// ---------------- x_proj: dbl(2048,80) = xa(2048,1536) @ w(1536,80), fp32 ---
__global__ void k_xproj(const float* __restrict__ xa, const float* __restrict__ w,
                        float* __restrict__ dbl) {
  const int t = threadIdx.x;               // 640 = 8 rows x 80 cols
  const int r = blockIdx.x * 8 + t / 80;
  const int c = t % 80;
  const float* xr = xa + (size_t)r * DINNER;
  float acc = 0.f;
  for (int k = 0; k < DINNER; k++) acc = fmaf(xr[k], w[k * 80 + c], acc);
  dbl[(size_t)r * 80 + c] = acc;
}

// ---------------- dt_proj + softplus, 8 rows/block (w_dt L2 reuse x8) -------
__global__ __launch_bounds__(256) void k_dtproj(
    const float* __restrict__ dbl, const float* __restrict__ w,
    const float* __restrict__ bvec, float* __restrict__ dt) {
  const int r0 = blockIdx.x * 8;
  const int tid = threadIdx.x;
  __shared__ float ds[8][DTRANK];
  for (int i = tid; i < 8 * DTRANK; i += 256)
    ds[i / DTRANK][i % DTRANK] = dbl[(size_t)(r0 + i / DTRANK) * 80 + i % DTRANK];
  __syncthreads();
  for (int c = tid; c < DINNER; c += 256) {
    const float bvc = bvec[c];
    float acc[8];
#pragma unroll
    for (int j = 0; j < 8; j++) acc[j] = bvc;
    for (int k = 0; k < DTRANK; k++) {
      const float wv = w[(size_t)k * DINNER + c];
#pragma unroll
      for (int j = 0; j < 8; j++) acc[j] = fmaf(ds[j][k], wv, acc[j]);
    }
#pragma unroll
    for (int j = 0; j < 8; j++) {
      const float a = acc[j];
      dt[(size_t)(r0 + j) * DINNER + c] = (a > 20.f) ? a : log1pf(expf(a));
    }
  }
}

// ======================= chunk-parallel selective scan =======================
__global__ __launch_bounds__(256) void k_scan1(
    const float* __restrict__ dt, const float* __restrict__ dbl,
    const float* __restrict__ xa, const float* __restrict__ a_log,
    float* __restrict__ P, float* __restrict__ S) {
  const int tid = threadIdx.x;
  const int d = blockIdx.x * 256 + tid;
  const int c = blockIdx.y;
  const int b = blockIdx.z;
  __shared__ float sB[CLEN][DSTATE];
  {
    const int j = tid >> 4, n = tid & 15;
    sB[j][n] = dbl[(size_t)(b * L_SEQ + c * CLEN + j) * 80 + DTRANK + n];
  }
  __syncthreads();
  float a[16];
#pragma unroll
  for (int q = 0; q < 4; q++) {
    const float4 v = *(const float4*)&a_log[d * DSTATE + q * 4];
    a[q*4+0] = -expf(v.x); a[q*4+1] = -expf(v.y);
    a[q*4+2] = -expf(v.z); a[q*4+3] = -expf(v.w);
  }
  float h[16] = {}, p[16];
#pragma unroll
  for (int n = 0; n < 16; n++) p[n] = 1.f;
  const size_t rowb = (size_t)(b * L_SEQ + c * CLEN);
#pragma unroll 4
  for (int j = 0; j < CLEN; j++) {
    const size_t row = rowb + j;
    const float dtv = dt[row * DINNER + d];
    const float xav = xa[row * DINNER + d];
    const float du  = dtv * xav;
#pragma unroll
    for (int n = 0; n < 16; n++) {
      const float dA = __expf(dtv * a[n]);
      h[n] = fmaf(dA, h[n], du * sB[j][n]);
      p[n] *= dA;
    }
  }
  const size_t base = (((size_t)c * B_SZ + b) * DINNER + d) * DSTATE;
#pragma unroll
  for (int q = 0; q < 4; q++) {
    *(float4*)&P[base + q * 4] = make_float4(p[q*4], p[q*4+1], p[q*4+2], p[q*4+3]);
    *(float4*)&S[base + q * 4] = make_float4(h[q*4], h[q*4+1], h[q*4+2], h[q*4+3]);
  }
}

__global__ __launch_bounds__(256) void k_scan2(
    const float* __restrict__ P, const float* __restrict__ S,
    float* __restrict__ Hin) {
  const int gid = blockIdx.x * 256 + threadIdx.x;   // (b*DINNER+d)*16+n
  const int STRIDE = B_SZ * DINNER * DSTATE;        // 49152
  float h = 0.f;
#pragma unroll 4
  for (int c = 0; c < NCH; c++) {
    Hin[(size_t)c * STRIDE + gid] = h;
    h = fmaf(P[(size_t)c * STRIDE + gid], h, S[(size_t)c * STRIDE + gid]);
  }
}

// scan3: re-scan with true h0, fused epilogue, writes hi/lo bf16 split of
// ycmb directly (feeds out_proj A operand)
__global__ __launch_bounds__(256) void k_scan3(
    const float* __restrict__ dt, const float* __restrict__ dbl,
    const float* __restrict__ xa, const float* __restrict__ a_log,
    const float* __restrict__ dvec, const float* __restrict__ xz,
    const float* __restrict__ Hin, bf16* __restrict__ ych,
    bf16* __restrict__ ycl) {
  const int tid = threadIdx.x;
  const int d = blockIdx.x * 256 + tid;
  const int c = blockIdx.y;
  const int b = blockIdx.z;
  __shared__ float sB[CLEN][DSTATE];
  __shared__ float sC[CLEN][DSTATE];
  {
    const int j = tid >> 4, n = tid & 15;
    const size_t r80 = (size_t)(b * L_SEQ + c * CLEN + j) * 80;
    sB[j][n] = dbl[r80 + DTRANK + n];
    sC[j][n] = dbl[r80 + DTRANK + DSTATE + n];
  }
  __syncthreads();
  float a[16];
#pragma unroll
  for (int q = 0; q < 4; q++) {
    const float4 v = *(const float4*)&a_log[d * DSTATE + q * 4];
    a[q*4+0] = -expf(v.x); a[q*4+1] = -expf(v.y);
    a[q*4+2] = -expf(v.z); a[q*4+3] = -expf(v.w);
  }
  float h[16];
  const size_t base = (((size_t)c * B_SZ + b) * DINNER + d) * DSTATE;
#pragma unroll
  for (int q = 0; q < 4; q++) {
    const float4 v = *(const float4*)&Hin[base + q * 4];
    h[q*4+0] = v.x; h[q*4+1] = v.y; h[q*4+2] = v.z; h[q*4+3] = v.w;
  }
  const float Dv = dvec[d];
  const size_t rowb = (size_t)(b * L_SEQ + c * CLEN);
#pragma unroll 4
  for (int j = 0; j < CLEN; j++) {
    const size_t row = rowb + j;
    const float dtv = dt[row * DINNER + d];
    const float xav = xa[row * DINNER + d];
    const float du  = dtv * xav;
    float y = 0.f;
#pragma unroll
    for (int n = 0; n < 16; n++) {
      const float dA = __expf(dtv * a[n]);
      h[n] = fmaf(dA, h[n], du * sB[j][n]);
      y = fmaf(h[n], sC[j][n], y);
    }
    const float z  = xz[row * (2 * DINNER) + DINNER + d];
    const float sz = z / (1.f + __expf(-z));
    const float val = fmaf(xav, Dv, y) * sz;
    const bf16 hv = (bf16)val;
    ych[row * DINNER + d] = hv;
    ycl[row * DINNER + d] = (bf16)(val - (float)hv);
  }
}

// ============================================================================
extern "C" void kernel_launch(void* const* d_in, const int* in_sizes, int n_in,
                              void* d_out, int out_size, void* d_ws, size_t ws_size,
                              hipStream_t stream) {
  const int*   ids   = (const int*)d_in[0];
  const float* emb   = (const float*)d_in[1];
  const float* w_in  = (const float*)d_in[2];   // 768 x 3072
  const float* cw    = (const float*)d_in[3];   // 1536 x 4
  const float* cb    = (const float*)d_in[4];
  const float* w_x   = (const float*)d_in[5];   // 1536 x 80
  const float* w_dt  = (const float*)d_in[6];   // 48 x 1536
  const float* b_dt  = (const float*)d_in[7];
  const float* a_log = (const float*)d_in[8];   // 1536 x 16
  const float* dvec  = (const float*)d_in[9];
  const float* w_out = (const float*)d_in[10];  // 1536 x 768
  const float* w_lm  = (const float*)d_in[11];  // 768 x 32000
  const float* b_lm  = (const float*)d_in[12];
  float* out = (float*)d_out;

  char* ws = (char*)d_ws;
  size_t off = 0;
  auto alloc = [&](size_t bytes) {
    void* p = ws + off;
    off = (off + bytes + 255) & ~(size_t)255;
    return p;
  };
  float* xw    = (float*)alloc((size_t)BL * DMODEL * 4);   // hosts Ap (3.1 MB)
  float* xz    = (float*)alloc((size_t)BL * 2 * DINNER * 4);
  float* xa    = (float*)alloc((size_t)BL * DINNER * 4);
  float* dbl   = (float*)alloc((size_t)BL * 80 * 4);
  float* dt    = (float*)alloc((size_t)BL * DINNER * 4);
  float* ycmb  = (float*)alloc((size_t)BL * DINNER * 4);   // (unused; layout kept)
  float* yo    = (float*)alloc((size_t)BL * DMODEL * 4);   // (unused; layout kept)
  bf16* xwh    = (bf16*)alloc((size_t)BL * DMODEL * 2);
  bf16* xwl    = (bf16*)alloc((size_t)BL * DMODEL * 2);
  bf16* wtinh  = (bf16*)alloc((size_t)3072 * DMODEL * 2);
  bf16* wtinl  = (bf16*)alloc((size_t)3072 * DMODEL * 2);
  bf16* ych    = (bf16*)alloc((size_t)BL * DINNER * 2);
  bf16* ycl    = (bf16*)alloc((size_t)BL * DINNER * 2);
  bf16* wtoh   = (bf16*)alloc((size_t)DMODEL * DINNER * 2);
  bf16* wtol   = (bf16*)alloc((size_t)DMODEL * DINNER * 2);
  bf16* yob    = (bf16*)alloc((size_t)BL * DMODEL * 2);
  bf16* wtlm   = (bf16*)alloc((size_t)VOCAB * DMODEL * 2); // hosts Bp (same size)
  (void)ycmb; (void)yo;
  if (off > ws_size) {
    fprintf(stderr, "kernel_launch: ws too small (need %zu, have %zu)\n", off, ws_size);
    return;
  }

  // Aliased scratch (dead-lifetime regions):
  //  P -> xwh+xwl (dead after in_proj GEMM); S -> ych+ycl (scan3 overwrites
  //  AFTER scan2 consumed S); Hin -> wtlm (consumed by scan3, then tconvp
  //  overwrites with Bp); Ap -> xw (never otherwise used).
  float* Pbuf = (float*)xwh;
  float* Sbuf = (float*)ych;
  float* Hin  = (float*)wtlm;
  bf16*  Bp   = wtlm;
  bf16*  Ap   = (bf16*)xw;

  // 1. embed fused with hi/lo split
  k_embed<<<BL, DMODEL / 4, 0, stream>>>(ids, emb, xwh, xwl);
  // 2. transpose-convert in_proj weight
  k_tconv<true><<<dim3(3072 / 32, DMODEL / 32), dim3(32, 8), 0, stream>>>(w_in, wtinh, wtinl, DMODEL, 3072);
  // 3. in_proj GEMM (split, fp32-exact-ish): xz = xw @ w_in
  k_gemm<true, false, false><<<dim3(3072 / 128, BL / 128), 256, 0, stream>>>(
      xwh, xwl, wtinh, wtinl, nullptr, xz, BL, 3072, DMODEL);
  // 4. conv + silu
  k_conv<<<BL, 256, 0, stream>>>(xz, cw, cb, xa);
  // 5. x_proj (fp32)
  k_xproj<<<BL / 8, 640, 0, stream>>>(xa, w_x, dbl);
  // 6. dt_proj + softplus (fp32, 8 rows/block)
  k_dtproj<<<BL / 8, 256, 0, stream>>>(dbl, w_dt, b_dt, dt);
  // 7. chunk-parallel scan; scan3 writes split bf16 directly
  k_scan1<<<dim3(DINNER / 256, NCH, B_SZ), 256, 0, stream>>>(dt, dbl, xa, a_log, Pbuf, Sbuf);
  k_scan2<<<(B_SZ * DINNER * DSTATE) / 256, 256, 0, stream>>>(Pbuf, Sbuf, Hin);
  k_scan3<<<dim3(DINNER / 256, NCH, B_SZ), 256, 0, stream>>>(dt, dbl, xa, a_log, dvec, xz, Hin, ych, ycl);
  // 8. out_proj GEMM (split), bf16 output fused (yob)
  k_tconv<true><<<dim3(DMODEL / 32, DINNER / 32), dim3(32, 8), 0, stream>>>(w_out, wtoh, wtol, DINNER, DMODEL);
  k_gemm<true, false, true><<<dim3(DMODEL / 128, BL / 128), 256, 0, stream>>>(
      ych, ycl, wtoh, wtol, nullptr, (float*)yob, BL, DMODEL, DINNER);
  // 9. lm_head: pack both operands into MFMA-fragment layout, then
  //    barrier-free direct-global GEMM
  k_tconvp<<<dim3(VOCAB / 32, DMODEL / 32), dim3(32, 8), 0, stream>>>(w_lm, Bp, DMODEL, VOCAB);
  k_apack<<<dim3(BL / 16, NKT), 64, 0, stream>>>(yob, Ap);
  {
    const int mb = BL / 128;                 // 16
    const int nb = VOCAB / 128;              // 250
    k_gemmp<<<mb * nb, 256, 0, stream>>>(Ap, Bp, b_lm, out, BL, VOCAB, mb);
  }
}

// Round 11
// 466.417 us; speedup vs baseline: 1.3018x; 1.0334x over previous
//
#include <hip/hip_runtime.h>
#include <hip/hip_bf16.h>
#include <cstdio>
#include <cstdint>

#define B_SZ    2
#define L_SEQ   1024
#define DMODEL  768
#define DINNER  1536
#define DSTATE  16
#define DTRANK  48
#define VOCAB   32000
#define BL      (B_SZ * L_SEQ)   // 2048
#define NCH     64               // scan chunks per sequence
#define CLEN    16               // timesteps per chunk (NCH*CLEN == L_SEQ)

typedef __bf16 bf16;
typedef __bf16 bf16x8 __attribute__((ext_vector_type(8)));
typedef __bf16 bf16x4 __attribute__((ext_vector_type(4)));
typedef float  f32x4  __attribute__((ext_vector_type(4)));

// ---------------- async global->LDS (16B/lane, wave-uniform base + lane*16) --
__device__ __forceinline__ void gload16(const void* g, void* l) {
  __builtin_amdgcn_global_load_lds(
      (const __attribute__((address_space(1))) void*)g,
      (__attribute__((address_space(3))) void*)l, 16, 0, 0);
}
__device__ __forceinline__ void memfence() { asm volatile("" ::: "memory"); }

// ---------------- embedding gather fused with hi/lo bf16 split --------------
__global__ void k_embed(const int* __restrict__ ids, const float* __restrict__ emb,
                        bf16* __restrict__ xh, bf16* __restrict__ xl) {
  const int row = blockIdx.x;
  const int id  = ids[row];
  const float4* s = (const float4*)(emb + (size_t)id * DMODEL);
  const int i = threadIdx.x;             // 192 threads = DMODEL/4
  const float4 v = s[i];
  bf16x4 hv, lv;
  hv[0] = (bf16)v.x; hv[1] = (bf16)v.y; hv[2] = (bf16)v.z; hv[3] = (bf16)v.w;
  lv[0] = (bf16)(v.x - (float)hv[0]); lv[1] = (bf16)(v.y - (float)hv[1]);
  lv[2] = (bf16)(v.z - (float)hv[2]); lv[3] = (bf16)(v.w - (float)hv[3]);
  *(bf16x4*)(xh + (size_t)row * DMODEL + i * 4) = hv;
  *(bf16x4*)(xl + (size_t)row * DMODEL + i * 4) = lv;
}

// ---------------- weight transpose + convert: W(K,N) f32 -> WT(N,K) bf16 ----
template<bool SPLIT>
__global__ void k_tconv(const float* __restrict__ W, bf16* __restrict__ Th,
                        bf16* __restrict__ Tl, int K, int N) {
  __shared__ float t[32][33];
  const int n0 = blockIdx.x * 32;
  const int k0 = blockIdx.y * 32;
  const int tx = threadIdx.x;   // 0..31
  const int ty = threadIdx.y;   // 0..7
#pragma unroll
  for (int i = 0; i < 4; i++)
    t[ty + i * 8][tx] = W[(size_t)(k0 + ty + i * 8) * N + n0 + tx];
  __syncthreads();
#pragma unroll
  for (int i = 0; i < 4; i++) {
    const float v = t[tx][ty + i * 8];
    const bf16 hv = (bf16)v;
    Th[(size_t)(n0 + ty + i * 8) * K + k0 + tx] = hv;
    if constexpr (SPLIT)
      Tl[(size_t)(n0 + ty + i * 8) * K + k0 + tx] = (bf16)(v - (float)hv);
  }
}

// ---------------- bf16 MFMA GEMM, 128x128, A+B LDS 2-buf (round-8 form) -----
// stage(t+1) issued BEFORE compute(t); one vmcnt(0)+barrier per K-tile.
// SPLIT: AhBh + AlBh + AhBl. BF16OUT: write C as bf16 (fused cvt).
template<bool SPLIT, bool BIAS, bool BF16OUT>
__global__ __launch_bounds__(256) void k_gemm(
    const bf16* __restrict__ Ah, const bf16* __restrict__ Al,
    const bf16* __restrict__ Bh, const bf16* __restrict__ Bl,
    const float* __restrict__ bias, float* __restrict__ C,
    int M, int N, int K) {
  __shared__ bf16 sAh[2][128 * 32];
  __shared__ bf16 sBh[2][128 * 32];
  __shared__ bf16 sAl[SPLIT ? 2 : 1][SPLIT ? 128 * 32 : 8];
  __shared__ bf16 sBl[SPLIT ? 2 : 1][SPLIT ? 128 * 32 : 8];

  const int tid  = threadIdx.x;
  const int lane = tid & 63;
  const int wave = tid >> 6;
  const int bm = blockIdx.y * 128;
  const int bn = blockIdx.x * 128;

  const int srow = tid >> 2;         // 0..63: staging row
  const int schk = (tid & 3) * 8;    // element offset in 32-wide K slab

  const bf16* gA0 = Ah + (size_t)(bm + srow) * K + schk;
  const bf16* gA1 = gA0 + (size_t)64 * K;
  const bf16* gB0 = Bh + (size_t)(bn + srow) * K + schk;
  const bf16* gB1 = gB0 + (size_t)64 * K;
  const bf16 *gA0l = nullptr, *gA1l = nullptr, *gB0l = nullptr, *gB1l = nullptr;
  if constexpr (SPLIT) {
    gA0l = Al + (size_t)(bm + srow) * K + schk;  gA1l = gA0l + (size_t)64 * K;
    gB0l = Bl + (size_t)(bn + srow) * K + schk;  gB1l = gB0l + (size_t)64 * K;
  }

  const int wm = (wave >> 1) * 64;
  const int wn = (wave & 1) * 64;
  const int lr = lane & 15;
  const int kg = lane >> 4;

  f32x4 acc[4][4] = {};
  const int nt = K >> 5;

#define STG(t_, b_) do {                                                    \
    const size_t ko_ = (size_t)(t_) * 32;                                   \
    gload16(gA0 + ko_, &sAh[b_][tid * 8]);                                  \
    gload16(gA1 + ko_, &sAh[b_][2048 + tid * 8]);                           \
    gload16(gB0 + ko_, &sBh[b_][tid * 8]);                                  \
    gload16(gB1 + ko_, &sBh[b_][2048 + tid * 8]);                           \
    if constexpr (SPLIT) {                                                  \
      gload16(gA0l + ko_, &sAl[b_][tid * 8]);                               \
      gload16(gA1l + ko_, &sAl[b_][2048 + tid * 8]);                        \
      gload16(gB0l + ko_, &sBl[b_][tid * 8]);                               \
      gload16(gB1l + ko_, &sBl[b_][2048 + tid * 8]);                        \
    }                                                                       \
  } while (0)

  STG(0, 0);
  asm volatile("s_waitcnt vmcnt(0)" ::: "memory");
  __builtin_amdgcn_s_barrier();
  memfence();

  for (int t = 0; t < nt; ++t) {
    const int b = t & 1;
    if (t + 1 < nt) STG(t + 1, b ^ 1);   // overlap next-tile staging w/ compute

    bf16x8 af[4], bfv[4];
#pragma unroll
    for (int i = 0; i < 4; i++)
      af[i] = *(const bf16x8*)&sAh[b][(wm + i * 16 + lr) * 32 + kg * 8];
#pragma unroll
    for (int i = 0; i < 4; i++)
      bfv[i] = *(const bf16x8*)&sBh[b][(wn + i * 16 + lr) * 32 + kg * 8];

#pragma unroll
    for (int mi = 0; mi < 4; mi++)
#pragma unroll
      for (int ni = 0; ni < 4; ni++)
        acc[mi][ni] = __builtin_amdgcn_mfma_f32_16x16x32_bf16(
            af[mi], bfv[ni], acc[mi][ni], 0, 0, 0);

    if constexpr (SPLIT) {
      bf16x8 afl[4], bfl[4];
#pragma unroll
      for (int i = 0; i < 4; i++)
        afl[i] = *(const bf16x8*)&sAl[b][(wm + i * 16 + lr) * 32 + kg * 8];
#pragma unroll
      for (int i = 0; i < 4; i++)
        bfl[i] = *(const bf16x8*)&sBl[b][(wn + i * 16 + lr) * 32 + kg * 8];
#pragma unroll
      for (int mi = 0; mi < 4; mi++)
#pragma unroll
        for (int ni = 0; ni < 4; ni++) {
          acc[mi][ni] = __builtin_amdgcn_mfma_f32_16x16x32_bf16(
              afl[mi], bfv[ni], acc[mi][ni], 0, 0, 0);
          acc[mi][ni] = __builtin_amdgcn_mfma_f32_16x16x32_bf16(
              af[mi], bfl[ni], acc[mi][ni], 0, 0, 0);
        }
    }

    asm volatile("s_waitcnt vmcnt(0)" ::: "memory");  // next tile landed
    __builtin_amdgcn_s_barrier();                     // all waves done w/ buf b
    memfence();
  }
#undef STG

#pragma unroll
  for (int mi = 0; mi < 4; mi++) {
#pragma unroll
    for (int ni = 0; ni < 4; ni++) {
      const int col = bn + wn + ni * 16 + lr;
      float bv = 0.f;
      if constexpr (BIAS) bv = bias[col];
#pragma unroll
      for (int r = 0; r < 4; r++) {
        const int row = bm + wm + mi * 16 + kg * 4 + r;
        if constexpr (BF16OUT)
          ((bf16*)C)[(size_t)row * N + col] = (bf16)(acc[mi][ni][r] + bv);
        else
          C[(size_t)row * N + col] = acc[mi][ni][r] + bv;
      }
    }
  }
}

// ========== lm_head GEMM: 256x256 block, 4 waves, wave-tile 128x128 =========
// Round-11 theory: the ~150us plateau across 4 structures traces to wave-tile
// arithmetic intensity WM*WN/(WM+WN): 64x64 -> 32 FLOP/B makes operand reads
// (LDS or L1, ~85 B/cyc/CU) >= MFMA work, and the per-wave read->MFMA chain
// serializes them. 128x128 wave tile -> 64 FLOP/B: LDS/CU/tile ~753 cyc vs
// MFMA ~1242 cyc -> MFMA-bound even at 1 block/CU. acc[8][8] f32x4 = 256
// regs; launch_bounds(256,1) grants the 512-reg budget (no spill < 450).
// Staging latency (~900 cyc) hides under the long per-tile compute.
// Swizzle as before: slot' = slot ^ ((row>>1)&3); row+64k preserves the key.
__global__ __launch_bounds__(256, 1) void k_gemmw(
    const bf16* __restrict__ A, const bf16* __restrict__ Bt,
    const float* __restrict__ bias, float* __restrict__ C,
    int M, int N, int K, int mblocks) {
  extern __shared__ bf16 lds[];   // [2 bufs][A 8192 el | B 8192 el] = 64 KB

  // T1: bijective XCD swizzle (gridDim.x % 8 == 0 guaranteed by host)
  const int orig = (blockIdx.x & 7) * ((int)gridDim.x >> 3) + (blockIdx.x >> 3);
  const int bm = (orig % mblocks) * 256;
  const int bn = (orig / mblocks) * 256;

  const int tid  = threadIdx.x;
  const int lane = tid & 63;
  const int wave = tid >> 6;       // 0..3
  const int wm   = wave >> 1;      // 0..1 : 128-row half
  const int wn   = wave & 1;       // 0..1 : 128-col half
  const int lr   = lane & 15;
  const int kg   = lane >> 4;      // 0..3 : 16B k-slot
  const int sw   = (lr >> 1) & 3;  // read-side swizzle key

  // staging: call c covers rows c*64 + (tid>>2); 4 calls per operand per tile
  const int srow  = tid >> 2;                        // 0..63
  const int sslot = (tid & 3) ^ ((srow >> 1) & 3);   // key invariant under +64
  const size_t gA = (size_t)(bm + srow) * K + sslot * 8;
  const size_t gB = (size_t)(bn + srow) * K + sslot * 8;

  // fragment read offsets within a buffer (elements, swizzled)
  const int aoff = (wm * 128 + lr) * 32 + ((kg ^ sw) << 3);
  const int boff = (wn * 128 + lr) * 32 + ((kg ^ sw) << 3);

  const int nt = K >> 5;   // 24

#define STAGE(ts_) do {                                                    \
    bf16* lb_ = lds + ((ts_) & 1) * 16384;                                 \
    const size_t ko_ = (size_t)(ts_) * 32;                                 \
    gload16(A  + gA + ko_,                  lb_ + tid * 8);                \
    gload16(A  + gA +  64 * (size_t)K + ko_, lb_ + 2048 + tid * 8);        \
    gload16(A  + gA + 128 * (size_t)K + ko_, lb_ + 4096 + tid * 8);        \
    gload16(A  + gA + 192 * (size_t)K + ko_, lb_ + 6144 + tid * 8);        \
    gload16(Bt + gB + ko_,                  lb_ + 8192 + tid * 8);         \
    gload16(Bt + gB +  64 * (size_t)K + ko_, lb_ + 10240 + tid * 8);       \
    gload16(Bt + gB + 128 * (size_t)K + ko_, lb_ + 12288 + tid * 8);       \
    gload16(Bt + gB + 192 * (size_t)K + ko_, lb_ + 14336 + tid * 8);       \
  } while (0)

  f32x4 acc[8][8] = {};

  STAGE(0);
  asm volatile("s_waitcnt vmcnt(0)" ::: "memory");
  __builtin_amdgcn_s_barrier();
  memfence();

  for (int t = 0; t < nt; ++t) {
    if (t + 1 < nt) STAGE(t + 1);   // issue prefetch BEFORE ds_read/MFMA

    const bf16* lA = lds + (t & 1) * 16384;
    const bf16* lB = lA + 8192;

    bf16x8 bfr[8], afr[8];
#pragma unroll
    for (int j = 0; j < 8; j++) bfr[j] = *(const bf16x8*)(lB + boff + j * 512);
#pragma unroll
    for (int i = 0; i < 8; i++) afr[i] = *(const bf16x8*)(lA + aoff + i * 512);

    __builtin_amdgcn_s_setprio(1);
#pragma unroll
    for (int i = 0; i < 8; i++)
#pragma unroll
      for (int j = 0; j < 8; j++)
        acc[i][j] = __builtin_amdgcn_mfma_f32_16x16x32_bf16(afr[i], bfr[j], acc[i][j], 0, 0, 0);
    __builtin_amdgcn_s_setprio(0);

    asm volatile("s_waitcnt vmcnt(0)" ::: "memory");  // tile t+1 landed
    __builtin_amdgcn_s_barrier();
    memfence();
  }
#undef STAGE

  // epilogue: C/D layout col=lane&15, row=(lane>>4)*4+r
  float bv[8];
#pragma unroll
  for (int j = 0; j < 8; j++)
    bv[j] = bias[bn + wn * 128 + j * 16 + lr];
#pragma unroll
  for (int i = 0; i < 8; i++) {
    const int row = bm + wm * 128 + i * 16 + kg * 4;
#pragma unroll
    for (int j = 0; j < 8; j++) {
      const int col = bn + wn * 128 + j * 16 + lr;
#pragma unroll
      for (int r = 0; r < 4; r++)
        C[(size_t)(row + r) * N + col] = acc[i][j][r] + bv[j];
    }
  }
}

// ---------------- depthwise causal conv (D_CONV=4) + silu -------------------
__global__ void k_conv(const float* __restrict__ xz, const float* __restrict__ cw,
                       const float* __restrict__ cb, float* __restrict__ xa) {
  const int bl = blockIdx.x;
  const int l  = bl & (L_SEQ - 1);
  for (int d = threadIdx.x; d < DINNER; d += blockDim.x) {
    float acc = cb[d];
#pragma unroll
    for (int k = 0; k < 4; k++) {
      const int ll = l + k - 3;
      if (ll >= 0)
        acc = fmaf(xz[(size_t)(bl + k - 3) * (2 * DINNER) + d], cw[d * 4 + k], acc);
    }
    xa[(size_t)bl * DINNER + d] = acc / (1.f + __expf(-acc));
  }
}

// ---------------- x_proj: dbl(2048,80) = xa(2048,1536) @ w(1536,80), fp32 ---
__global__ void k_xproj(const float* __restrict__ xa, const float* __restrict__ w,
                        float* __restrict__ dbl) {
  const int t = threadIdx.x;               // 640 = 8 rows x 80 cols
  const int r = blockIdx.x * 8 + t / 80;
  const int c = t % 80;
  const float* xr = xa + (size_t)r * DINNER;
  float acc = 0.f;
  for (int k = 0; k < DINNER; k++) acc = fmaf(xr[k], w[k * 80 + c], acc);
  dbl[(size_t)r * 80 + c] = acc;
}

// ---------------- dt_proj + softplus, 8 rows/block (w_dt L2 reuse x8) -------
__global__ __launch_bounds__(256) void k_dtproj(
    const float* __restrict__ dbl, const float* __restrict__ w,
    const float* __restrict__ bvec, float* __restrict__ dt) {
  const int r0 = blockIdx.x * 8;
  const int tid = threadIdx.x;
  __shared__ float ds[8][DTRANK];
  for (int i = tid; i < 8 * DTRANK; i += 256)
    ds[i / DTRANK][i % DTRANK] = dbl[(size_t)(r0 + i / DTRANK) * 80 + i % DTRANK];
  __syncthreads();
  for (int c = tid; c < DINNER; c += 256) {
    const float bvc = bvec[c];
    float acc[8];
#pragma unroll
    for (int j = 0; j < 8; j++) acc[j] = bvc;
    for (int k = 0; k < DTRANK; k++) {
      const float wv = w[(size_t)k * DINNER + c];
#pragma unroll
      for (int j = 0; j < 8; j++) acc[j] = fmaf(ds[j][k], wv, acc[j]);
    }
#pragma unroll
    for (int j = 0; j < 8; j++) {
      const float a = acc[j];
      dt[(size_t)(r0 + j) * DINNER + c] = (a > 20.f) ? a : log1pf(expf(a));
    }
  }
}

// ======================= chunk-parallel selective scan =======================
__global__ __launch_bounds__(256) void k_scan1(
    const float* __restrict__ dt, const float* __restrict__ dbl,
    const float* __restrict__ xa, const float* __restrict__ a_log,
    float* __restrict__ P, float* __restrict__ S) {
  const int tid = threadIdx.x;
  const int d = blockIdx.x * 256 + tid;
  const int c = blockIdx.y;
  const int b = blockIdx.z;
  __shared__ float sB[CLEN][DSTATE];
  {
    const int j = tid >> 4, n = tid & 15;
    sB[j][n] = dbl[(size_t)(b * L_SEQ + c * CLEN + j) * 80 + DTRANK + n];
  }
  __syncthreads();
  float a[16];
#pragma unroll
  for (int q = 0; q < 4; q++) {
    const float4 v = *(const float4*)&a_log[d * DSTATE + q * 4];
    a[q*4+0] = -expf(v.x); a[q*4+1] = -expf(v.y);
    a[q*4+2] = -expf(v.z); a[q*4+3] = -expf(v.w);
  }
  float h[16] = {}, p[16];
#pragma unroll
  for (int n = 0; n < 16; n++) p[n] = 1.f;
  const size_t rowb = (size_t)(b * L_SEQ + c * CLEN);
#pragma unroll 4
  for (int j = 0; j < CLEN; j++) {
    const size_t row = rowb + j;
    const float dtv = dt[row * DINNER + d];
    const float xav = xa[row * DINNER + d];
    const float du  = dtv * xav;
#pragma unroll
    for (int n = 0; n < 16; n++) {
      const float dA = __expf(dtv * a[n]);
      h[n] = fmaf(dA, h[n], du * sB[j][n]);
      p[n] *= dA;
    }
  }
  const size_t base = (((size_t)c * B_SZ + b) * DINNER + d) * DSTATE;
#pragma unroll
  for (int q = 0; q < 4; q++) {
    *(float4*)&P[base + q * 4] = make_float4(p[q*4], p[q*4+1], p[q*4+2], p[q*4+3]);
    *(float4*)&S[base + q * 4] = make_float4(h[q*4], h[q*4+1], h[q*4+2], h[q*4+3]);
  }
}

__global__ __launch_bounds__(256) void k_scan2(
    const float* __restrict__ P, const float* __restrict__ S,
    float* __restrict__ Hin) {
  const int gid = blockIdx.x * 256 + threadIdx.x;   // (b*DINNER+d)*16+n
  const int STRIDE = B_SZ * DINNER * DSTATE;        // 49152
  float h = 0.f;
#pragma unroll 4
  for (int c = 0; c < NCH; c++) {
    Hin[(size_t)c * STRIDE + gid] = h;
    h = fmaf(P[(size_t)c * STRIDE + gid], h, S[(size_t)c * STRIDE + gid]);
  }
}

// scan3: re-scan with true h0, fused epilogue, writes hi/lo bf16 split of
// ycmb directly (feeds out_proj A operand)
__global__ __launch_bounds__(256) void k_scan3(
    const float* __restrict__ dt, const float* __restrict__ dbl,
    const float* __restrict__ xa, const float* __restrict__ a_log,
    const float* __restrict__ dvec, const float* __restrict__ xz,
    const float* __restrict__ Hin, bf16* __restrict__ ych,
    bf16* __restrict__ ycl) {
  const int tid = threadIdx.x;
  const int d = blockIdx.x * 256 + tid;
  const int c = blockIdx.y;
  const int b = blockIdx.z;
  __shared__ float sB[CLEN][DSTATE];
  __shared__ float sC[CLEN][DSTATE];
  {
    const int j = tid >> 4, n = tid & 15;
    const size_t r80 = (size_t)(b * L_SEQ + c * CLEN + j) * 80;
    sB[j][n] = dbl[r80 + DTRANK + n];
    sC[j][n] = dbl[r80 + DTRANK + DSTATE + n];
  }
  __syncthreads();
  float a[16];
#pragma unroll
  for (int q = 0; q < 4; q++) {
    const float4 v = *(const float4*)&a_log[d * DSTATE + q * 4];
    a[q*4+0] = -expf(v.x); a[q*4+1] = -expf(v.y);
    a[q*4+2] = -expf(v.z); a[q*4+3] = -expf(v.w);
  }
  float h[16];
  const size_t base = (((size_t)c * B_SZ + b) * DINNER + d) * DSTATE;
#pragma unroll
  for (int q = 0; q < 4; q++) {
    const float4 v = *(const float4*)&Hin[base + q * 4];
    h[q*4+0] = v.x; h[q*4+1] = v.y; h[q*4+2] = v.z; h[q*4+3] = v.w;
  }
  const float Dv = dvec[d];
  const size_t rowb = (size_t)(b * L_SEQ + c * CLEN);
#pragma unroll 4
  for (int j = 0; j < CLEN; j++) {
    const size_t row = rowb + j;
    const float dtv = dt[row * DINNER + d];
    const float xav = xa[row * DINNER + d];
    const float du  = dtv * xav;
    float y = 0.f;
#pragma unroll
    for (int n = 0; n < 16; n++) {
      const float dA = __expf(dtv * a[n]);
      h[n] = fmaf(dA, h[n], du * sB[j][n]);
      y = fmaf(h[n], sC[j][n], y);
    }
    const float z  = xz[row * (2 * DINNER) + DINNER + d];
    const float sz = z / (1.f + __expf(-z));
    const float val = fmaf(xav, Dv, y) * sz;
    const bf16 hv = (bf16)val;
    ych[row * DINNER + d] = hv;
    ycl[row * DINNER + d] = (bf16)(val - (float)hv);
  }
}

// ============================================================================
extern "C" void kernel_launch(void* const* d_in, const int* in_sizes, int n_in,
                              void* d_out, int out_size, void* d_ws, size_t ws_size,
                              hipStream_t stream) {
  const int*   ids   = (const int*)d_in[0];
  const float* emb   = (const float*)d_in[1];
  const float* w_in  = (const float*)d_in[2];   // 768 x 3072
  const float* cw    = (const float*)d_in[3];   // 1536 x 4
  const float* cb    = (const float*)d_in[4];
  const float* w_x   = (const float*)d_in[5];   // 1536 x 80
  const float* w_dt  = (const float*)d_in[6];   // 48 x 1536
  const float* b_dt  = (const float*)d_in[7];
  const float* a_log = (const float*)d_in[8];   // 1536 x 16
  const float* dvec  = (const float*)d_in[9];
  const float* w_out = (const float*)d_in[10];  // 1536 x 768
  const float* w_lm  = (const float*)d_in[11];  // 768 x 32000
  const float* b_lm  = (const float*)d_in[12];
  float* out = (float*)d_out;

  char* ws = (char*)d_ws;
  size_t off = 0;
  auto alloc = [&](size_t bytes) {
    void* p = ws + off;
    off = (off + bytes + 255) & ~(size_t)255;
    return p;
  };
  float* xw    = (float*)alloc((size_t)BL * DMODEL * 4);   // (spare)
  float* xz    = (float*)alloc((size_t)BL * 2 * DINNER * 4);
  float* xa    = (float*)alloc((size_t)BL * DINNER * 4);
  float* dbl   = (float*)alloc((size_t)BL * 80 * 4);
  float* dt    = (float*)alloc((size_t)BL * DINNER * 4);
  float* ycmb  = (float*)alloc((size_t)BL * DINNER * 4);   // (spare)
  float* yo    = (float*)alloc((size_t)BL * DMODEL * 4);   // (spare)
  bf16* xwh    = (bf16*)alloc((size_t)BL * DMODEL * 2);
  bf16* xwl    = (bf16*)alloc((size_t)BL * DMODEL * 2);
  bf16* wtinh  = (bf16*)alloc((size_t)3072 * DMODEL * 2);
  bf16* wtinl  = (bf16*)alloc((size_t)3072 * DMODEL * 2);
  bf16* ych    = (bf16*)alloc((size_t)BL * DINNER * 2);
  bf16* ycl    = (bf16*)alloc((size_t)BL * DINNER * 2);
  bf16* wtoh   = (bf16*)alloc((size_t)DMODEL * DINNER * 2);
  bf16* wtol   = (bf16*)alloc((size_t)DMODEL * DINNER * 2);
  bf16* yob    = (bf16*)alloc((size_t)BL * DMODEL * 2);
  bf16* wtlm   = (bf16*)alloc((size_t)VOCAB * DMODEL * 2);
  (void)xw; (void)ycmb; (void)yo;
  if (off > ws_size) {
    fprintf(stderr, "kernel_launch: ws too small (need %zu, have %zu)\n", off, ws_size);
    return;
  }

  // Aliased scratch (dead-lifetime regions):
  //  P -> xwh+xwl (dead after in_proj GEMM); S -> ych+ycl (scan3 overwrites
  //  AFTER scan2 consumed S); Hin -> wtlm (consumed by scan3, then tconv_lm
  //  overwrites).
  float* Pbuf = (float*)xwh;
  float* Sbuf = (float*)ych;
  float* Hin  = (float*)wtlm;

  (void)hipFuncSetAttribute((const void*)k_gemmw,
                            hipFuncAttributeMaxDynamicSharedMemorySize, 65536);

  // 1. embed fused with hi/lo split
  k_embed<<<BL, DMODEL / 4, 0, stream>>>(ids, emb, xwh, xwl);
  // 2. transpose-convert in_proj weight
  k_tconv<true><<<dim3(3072 / 32, DMODEL / 32), dim3(32, 8), 0, stream>>>(w_in, wtinh, wtinl, DMODEL, 3072);
  // 3. in_proj GEMM (split, fp32-exact-ish): xz = xw @ w_in
  k_gemm<true, false, false><<<dim3(3072 / 128, BL / 128), 256, 0, stream>>>(
      xwh, xwl, wtinh, wtinl, nullptr, xz, BL, 3072, DMODEL);
  // 4. conv + silu
  k_conv<<<BL, 256, 0, stream>>>(xz, cw, cb, xa);
  // 5. x_proj (fp32)
  k_xproj<<<BL / 8, 640, 0, stream>>>(xa, w_x, dbl);
  // 6. dt_proj + softplus (fp32, 8 rows/block)
  k_dtproj<<<BL / 8, 256, 0, stream>>>(dbl, w_dt, b_dt, dt);
  // 7. chunk-parallel scan; scan3 writes split bf16 directly
  k_scan1<<<dim3(DINNER / 256, NCH, B_SZ), 256, 0, stream>>>(dt, dbl, xa, a_log, Pbuf, Sbuf);
  k_scan2<<<(B_SZ * DINNER * DSTATE) / 256, 256, 0, stream>>>(Pbuf, Sbuf, Hin);
  k_scan3<<<dim3(DINNER / 256, NCH, B_SZ), 256, 0, stream>>>(dt, dbl, xa, a_log, dvec, xz, Hin, ych, ycl);
  // 8. out_proj GEMM (split), bf16 output fused (yob)
  k_tconv<true><<<dim3(DMODEL / 32, DINNER / 32), dim3(32, 8), 0, stream>>>(w_out, wtoh, wtol, DINNER, DMODEL);
  k_gemm<true, false, true><<<dim3(DMODEL / 128, BL / 128), 256, 0, stream>>>(
      ych, ycl, wtoh, wtol, nullptr, (float*)yob, BL, DMODEL, DINNER);
  // 9. lm_head GEMM: 256x256 block / wave-tile 128x128, bf16 + fp32 bias
  k_tconv<false><<<dim3(VOCAB / 32, DMODEL / 32), dim3(32, 8), 0, stream>>>(w_lm, wtlm, nullptr, DMODEL, VOCAB);
  {
    const int mb = BL / 256;                 // 8
    const int nb = VOCAB / 256;              // 125
    k_gemmw<<<mb * nb, 256, 65536, stream>>>(yob, wtlm, b_lm, out,
                                             BL, VOCAB, DMODEL, mb);
  }
}